// Round 15
// baseline (742.440 us; speedup 1.0000x reference)
//
#include <hip/hip_runtime.h>
#include <hip/hip_bf16.h>
#include <stdint.h>

#define M_TOT 8192
#define N_TOT 16384
#define K_TOT 4096

typedef int v4i __attribute__((ext_vector_type(4)));
typedef int v16i __attribute__((ext_vector_type(16)));

__device__ __forceinline__ float fix_scale(float s) { return s == 0.0f ? 1.0f : s; }

__device__ __forceinline__ void gload_lds16(const void* g, void* l) {
    __builtin_amdgcn_global_load_lds((__attribute__((address_space(1))) void*)g,
                                     (__attribute__((address_space(3))) void*)l,
                                     16, 0, 0);
}

__device__ __forceinline__ int8_t quant1(float x, float scale) {
    float r = fminf(127.0f, fmaxf(-127.0f, rintf(x / scale)));
    return (int8_t)(int)r;
}

__device__ __forceinline__ unsigned pack4(float4 v, float scale) {
    unsigned b0 = (unsigned char)quant1(v.x, scale);
    unsigned b1 = (unsigned char)quant1(v.y, scale);
    unsigned b2 = (unsigned char)quant1(v.z, scale);
    unsigned b3 = (unsigned char)quant1(v.w, scale);
    return b0 | (b1 << 8) | (b2 << 16) | (b3 << 24);
}

// Tiled fragment-major operand layout (16 KB chunks per (tile,kt)) for 32x32 frags:
//   granule g = (frag*2 + s)*64 + h*32 + r  holds  row/col = tile*256 + frag*32 + r,
//   k-bytes kt*64 + s*32 + h*16 .. +15.
// GEMM fragment read = contiguous 1 KB per wave (bank-conflict-free);
// GEMM staging = contiguous 16 KB chunk copies (ideal coalescing).

// ---------------- lhs: per-row absmax quantize -> tiled qA_t ----------------
__global__ __launch_bounds__(256) void k_quant_lhs(const float* __restrict__ x,
                                                   int8_t* __restrict__ qt,
                                                   float* __restrict__ s) {
    const int row = blockIdx.x;
    const int t = threadIdx.x;
    const float4* xr = (const float4*)(x + (size_t)row * K_TOT);
    float4 v[4];
    float m = 0.0f;
#pragma unroll
    for (int i = 0; i < 4; ++i) {
        v[i] = xr[t * 4 + i];   // thread owns k-elems 16t .. 16t+15
        m = fmaxf(m, fmaxf(fmaxf(fabsf(v[i].x), fabsf(v[i].y)),
                           fmaxf(fabsf(v[i].z), fabsf(v[i].w))));
    }
#pragma unroll
    for (int off = 32; off; off >>= 1) m = fmaxf(m, __shfl_xor(m, off));
    __shared__ float wmax[4];
    if ((t & 63) == 0) wmax[t >> 6] = m;
    __syncthreads();
    m = fmaxf(fmaxf(wmax[0], wmax[1]), fmaxf(wmax[2], wmax[3]));
    const float scale = fix_scale(m / 127.0f);
    if (t == 0) s[row] = scale;

    v4i w;
#pragma unroll
    for (int i = 0; i < 4; ++i) w[i] = (int)pack4(v[i], scale);

    const int mt = row >> 8, mb = (row >> 5) & 7, r = row & 31;
    const int kt = t >> 2, s2 = (t >> 1) & 1, h = t & 1;
    const size_t gidx = (size_t)(mt * 64 + kt) * 1024 + (size_t)((mb * 2 + s2) * 64 + h * 32 + r);
    ((v4i*)qt)[gidx] = w;
}

// ---------------- rhs: per-column absmax (atomicMax on float bits) ----------------
__global__ __launch_bounds__(256) void k_rhs_absmax(const float* __restrict__ rhs,
                                                    unsigned* __restrict__ amax) {
    const int f = blockIdx.x * 256 + threadIdx.x;
    const int d0 = blockIdx.y * 256;
    const float* p = rhs + (size_t)d0 * N_TOT + f;
    float m = 0.0f;
#pragma unroll 4
    for (int d = 0; d < 256; ++d)
        m = fmaxf(m, fabsf(p[(size_t)d * N_TOT]));
    atomicMax(amax + f, __float_as_uint(m));
}

// ------- rhs: quantize + transpose -> tiled qB_t (scale fused; writes sB at y==0) -------
__global__ __launch_bounds__(256) void k_quant_rhs_t(const float* __restrict__ rhs,
                                                     const unsigned* __restrict__ amax,
                                                     float* __restrict__ sB,
                                                     int8_t* __restrict__ qt) {
    const int f0 = blockIdx.x * 64;   // col base (multiple of 64)
    const int d0 = blockIdx.y * 64;   // k base
    const int t = threadIdx.x;
    __shared__ float sc[64];
    __shared__ alignas(16) int8_t tile[64][64];  // [col local][k local]
    if (t < 64) {
        const float scale = fix_scale(__uint_as_float(amax[f0 + t]) / 127.0f);
        sc[t] = scale;
        if (blockIdx.y == 0) sB[f0 + t] = scale;
    }
    __syncthreads();
    const int fl = (t & 15) * 4;
    const int rl = t >> 4;
#pragma unroll
    for (int i = 0; i < 4; ++i) {
        const int dl = i * 16 + rl;
        float4 v = *(const float4*)(rhs + (size_t)(d0 + dl) * N_TOT + f0 + fl);
        tile[fl + 0][dl] = quant1(v.x, sc[fl + 0]);
        tile[fl + 1][dl] = quant1(v.y, sc[fl + 1]);
        tile[fl + 2][dl] = quant1(v.z, sc[fl + 2]);
        tile[fl + 3][dl] = quant1(v.w, sc[fl + 3]);
    }
    __syncthreads();
    // one 16B granule per thread, tiled-layout ordering (BN tile = 256 cols)
    const int nb_l = t >> 7, s2 = (t >> 6) & 1, h = (t >> 5) & 1, r = t & 31;
    const int col_local = nb_l * 32 + r;
    const int kb16 = s2 * 2 + h;
    const int nt = f0 >> 8;                      // 256-col tile index
    const int nb = ((f0 >> 5) & 7) + nb_l;       // 32-col frag within tile
    const int kt = d0 >> 6;
    const size_t gidx = (size_t)(nt * 64 + kt) * 1024 + (size_t)((nb * 2 + s2) * 64 + h * 32 + r);
    ((v4i*)qt)[gidx] = *(const v4i*)&tile[col_local][kb16 * 16];
}

// ---- int8 GEMM: 256x256 tile, 8 waves of 128x64 (32x32x32), 2-phase-per-kt schedule ----
// (round-11 structure: measured best, 553 us / MfmaUtil 46.2%)
#define BM 256
#define BN 256
#define BK 64
#define NKT (K_TOT / BK)   // 64

#define MFMA_I8(A, B, Cc) __builtin_amdgcn_mfma_i32_32x32x32_i8((A), (B), (Cc), 0, 0, 0)

__global__ __launch_bounds__(512, 2) void k_gemm(const int8_t* __restrict__ qA,   // tiled
                                                 const int8_t* __restrict__ qB,   // tiled
                                                 const float* __restrict__ sA,
                                                 const float* __restrict__ sB,
                                                 float* __restrict__ C) {
    // 3-deep buffer: per K-tile chunk = A 16KB + B 16KB
    __shared__ alignas(1024) int8_t lds[3][32768];   // 96 KB -> 1 block/CU

    // supercolumn raster: 2 bn-tiles wide (verified FETCH ~394 MB)
    const int bid = blockIdx.x;          // 0..2047
    const int scc = bid >> 6;            // 32 supercolumns
    const int ii = bid & 63;
    const int mt = ii & 31;
    const int ntile = (scc << 1) | (ii >> 5);
    const int bm0 = mt << 8;
    const int bn0 = ntile << 8;

    const int tid = threadIdx.x;         // 0..511
    const int wave = tid >> 6;
    const int lane = tid & 63;
    const int wm = (wave >> 2) * 128;    // 2 wave-rows
    const int wn = (wave & 3) * 64;      // 4 wave-cols

    const int8_t* aBase = qA + (size_t)mt * (64 * 16384);
    const int8_t* bBase = qB + (size_t)ntile * (64 * 16384);

    // fragment offsets (lane-contiguous 1KB): A frag f slice s: aoff + f*2048 + s*1024
    const int aoff = (wave >> 2) * 8192 + lane * 16;
    const int boff = 16384 + (wave & 3) * 4096 + lane * 16;   // + n*2048 + s*1024

    v16i acc[4][2];
#pragma unroll
    for (int f = 0; f < 4; ++f)
#pragma unroll
        for (int n = 0; n < 2; ++n)
#pragma unroll
            for (int e = 0; e < 16; ++e) acc[f][n][e] = 0;

    // half-tile stage: h=0,1 -> A halves; h=2,3 -> B halves (1 gload/thread each)
    auto stage_half = [&](int kt, int h) {
        const int b = kt % 3;
        const int loff = h * 8192 + tid * 16;
        const int8_t* src = (h < 2) ? (aBase + (size_t)kt * 16384 + h * 8192 + tid * 16)
                                    : (bBase + (size_t)kt * 16384 + (h - 2) * 8192 + tid * 16);
        gload_lds16(src, &lds[b][loff]);
    };

    // prologue: fully stage kt=0 and kt=1 (8 loads); wait kt0's 4, keep kt1's in flight
    stage_half(0, 0); stage_half(0, 1); stage_half(0, 2); stage_half(0, 3);
    stage_half(1, 0); stage_half(1, 1); stage_half(1, 2); stage_half(1, 3);
    asm volatile("s_waitcnt vmcnt(4)" ::: "memory");
    __builtin_amdgcn_s_barrier();

    for (int kt = 0; kt < NKT; ++kt) {
        const int8_t* a = &lds[kt % 3][0];
        const bool st = (kt + 2 < NKT);
        v4i af[4], bf[2];

        // ======== phase 0: slice 0 (A f0-3 + B n0-1), stage A halves ========
        af[0] = *(const v4i*)(a + aoff + 0 * 2048);
        af[1] = *(const v4i*)(a + aoff + 1 * 2048);
        af[2] = *(const v4i*)(a + aoff + 2 * 2048);
        af[3] = *(const v4i*)(a + aoff + 3 * 2048);
        bf[0] = *(const v4i*)(a + boff + 0 * 2048);
        bf[1] = *(const v4i*)(a + boff + 1 * 2048);
        if (st) { stage_half(kt + 2, 0); stage_half(kt + 2, 1); }
        __builtin_amdgcn_s_barrier();
        asm volatile("s_waitcnt lgkmcnt(0)" ::: "memory");
        __builtin_amdgcn_s_setprio(1);
        acc[0][0] = MFMA_I8(af[0], bf[0], acc[0][0]);
        acc[0][1] = MFMA_I8(af[0], bf[1], acc[0][1]);
        acc[1][0] = MFMA_I8(af[1], bf[0], acc[1][0]);
        acc[1][1] = MFMA_I8(af[1], bf[1], acc[1][1]);
        acc[2][0] = MFMA_I8(af[2], bf[0], acc[2][0]);
        acc[2][1] = MFMA_I8(af[2], bf[1], acc[2][1]);
        acc[3][0] = MFMA_I8(af[3], bf[0], acc[3][0]);
        acc[3][1] = MFMA_I8(af[3], bf[1], acc[3][1]);
        __builtin_amdgcn_s_setprio(0);
        __builtin_amdgcn_s_barrier();

        // ======== phase 1: slice 1 (A f0-3 + B n0-1), stage B halves ========
        af[0] = *(const v4i*)(a + aoff + 0 * 2048 + 1024);
        af[1] = *(const v4i*)(a + aoff + 1 * 2048 + 1024);
        af[2] = *(const v4i*)(a + aoff + 2 * 2048 + 1024);
        af[3] = *(const v4i*)(a + aoff + 3 * 2048 + 1024);
        bf[0] = *(const v4i*)(a + boff + 0 * 2048 + 1024);
        bf[1] = *(const v4i*)(a + boff + 1 * 2048 + 1024);
        if (st) { stage_half(kt + 2, 2); stage_half(kt + 2, 3); }
        __builtin_amdgcn_s_barrier();
        asm volatile("s_waitcnt lgkmcnt(0)" ::: "memory");
        __builtin_amdgcn_s_setprio(1);
        acc[0][0] = MFMA_I8(af[0], bf[0], acc[0][0]);
        acc[0][1] = MFMA_I8(af[0], bf[1], acc[0][1]);
        acc[1][0] = MFMA_I8(af[1], bf[0], acc[1][0]);
        acc[1][1] = MFMA_I8(af[1], bf[1], acc[1][1]);
        acc[2][0] = MFMA_I8(af[2], bf[0], acc[2][0]);
        acc[2][1] = MFMA_I8(af[2], bf[1], acc[2][1]);
        acc[3][0] = MFMA_I8(af[3], bf[0], acc[3][0]);
        acc[3][1] = MFMA_I8(af[3], bf[1], acc[3][1]);
        __builtin_amdgcn_s_setprio(0);
        // one counted vmcnt per K-tile (never 0 in steady state): kt+1's 4 loads
        // complete after this barrier; kt+2's 4 stay in flight.
        if (kt + 2 < NKT)      asm volatile("s_waitcnt vmcnt(4)" ::: "memory");
        else if (kt + 1 < NKT) asm volatile("s_waitcnt vmcnt(0)" ::: "memory");
        __builtin_amdgcn_s_barrier();
    }

    // epilogue: dequant + store. 32x32 C/D: col = lane&31, row = (r&3)+8*(r>>2)+4*(lane>>5)
    const int cc0 = lane & 31;
    const int rbase = (lane >> 5) * 4;
#pragma unroll
    for (int f = 0; f < 4; ++f) {
#pragma unroll
        for (int r = 0; r < 16; ++r) {
            const int gr = bm0 + wm + f * 32 + (r & 3) + 8 * (r >> 2) + rbase;
            const float sa = sA[gr];
            float* crow = C + (size_t)gr * N_TOT + bn0 + wn;
#pragma unroll
            for (int n = 0; n < 2; ++n)
                crow[n * 32 + cc0] = (float)acc[f][n][r] * sa * sB[bn0 + wn + n * 32 + cc0];
        }
    }
}

extern "C" void kernel_launch(void* const* d_in, const int* in_sizes, int n_in,
                              void* d_out, int out_size, void* d_ws, size_t ws_size,
                              hipStream_t stream) {
    const float* lhs = (const float*)d_in[0];
    const float* rhs = (const float*)d_in[1];
    float* out = (float*)d_out;
    char* ws = (char*)d_ws;

    int8_t* qA = (int8_t*)ws;                                   // 32 MB (tiled)
    int8_t* qB = (int8_t*)(ws + (size_t)33554432);              // 64 MB (tiled)
    float* sA = (float*)(ws + (size_t)33554432 + 67108864);     // 32 KB
    float* sB = sA + M_TOT;                                     // 64 KB
    unsigned* amax = (unsigned*)(sB + N_TOT);                   // 64 KB

    hipMemsetAsync(amax, 0, N_TOT * sizeof(unsigned), stream);

    k_quant_lhs<<<M_TOT, 256, 0, stream>>>(lhs, qA, sA);
    k_rhs_absmax<<<dim3(N_TOT / 256, K_TOT / 256), 256, 0, stream>>>(rhs, amax);
    k_quant_rhs_t<<<dim3(N_TOT / 64, K_TOT / 64), 256, 0, stream>>>(rhs, amax, sB, qB);
    k_gemm<<<(M_TOT / BM) * (N_TOT / BN), 512, 0, stream>>>(qA, qB, sA, sB, out);
}